// Round 9
// baseline (290.704 us; speedup 1.0000x reference)
//
#include <hip/hip_runtime.h>

typedef _Float16 f16;
typedef f16 f16x8 __attribute__((ext_vector_type(8)));
typedef f16 f16x4v __attribute__((ext_vector_type(4)));
typedef float f32x4 __attribute__((ext_vector_type(4)));
typedef float f32x16 __attribute__((ext_vector_type(16)));

// async global->LDS, 16B per lane. LDS dest is wave-uniform base; HW scatters
// lane i's 16B to base + i*16. (No padding possible -> keep BK=32 layout.)
// NOTE (r6): direct per-fragment global loads instead of LDS staging regress
// 4x (MfmaUtil 4.5%) -- exposed VMEM latency. Keep LDS staging.
__device__ __forceinline__ void async_ld16(const void* g, void* l) {
    __builtin_amdgcn_global_load_lds(
        (const __attribute__((address_space(1))) unsigned int*)g,
        (__attribute__((address_space(3))) unsigned int*)l, 16, 0, 0);
}

// C[m,n] = sum_k A[m,k] * Bt[n,k], tile 128 x 128, K-step 64 = 2 x BK32.
// r9: MFMA shape switched 16x16x32 -> 32x32x16 (m119: 2495 vs 2176 TF
// ceiling; half the issue slots). Frag layouts (m74/m101/m119):
//   A/B: elem j of lane l -> [m|n = l&31][k = 8*(l>>5) + j]
//   C/D: col = l&31, row = (reg&3) + 8*(reg>>2) + 4*(l>>5), reg in [0,16)
// MODE 0: 256 thr (4 waves, 64x64/wave, MI=2). fused QKV, N=3072;
//       seg(nBase>>10): 0 -> Q16 (+b_q), 1 -> K16 (+b_k),
//       2 -> Vt16 [b][e][s] via LDS transpose.
// MODE 2: 512 thr (8 waves, 32x64/wave, MI=1; r7: these grids are
//       block-starved so fatter blocks raise waves/CU).
//       P[q][k] = exp(score/32) f16, causal-zeroed; rowsum atomics.
// MODE 3: 512 thr. out = (P @ V) / rowsum[q], fp32; K-loop causal-limited.
template <int MODE>
__global__ __launch_bounds__((MODE == 0) ? 256 : 512) void gemm_bt(
    const f16* __restrict__ A, long strideAb, int lda,
    const f16* __restrict__ Bt, long strideBb, int ldb,
    const float* __restrict__ b_q, const float* __restrict__ b_k,
    const float* __restrict__ b_v, float* __restrict__ rowsum,
    void* __restrict__ C0, void* __restrict__ C1, void* __restrict__ C2,
    long strideCb, int K,
    const int* __restrict__ maskedp)
{
    constexpr int NT  = (MODE == 0) ? 256 : 512;   // threads
    constexpr int MI  = (MODE == 0) ? 2 : 1;       // 32-row MFMA tiles per wave
    constexpr int RND = (128 * 32) / (NT * 8);     // staging rounds per subtile

    const int bx = blockIdx.x, bz = blockIdx.z;
    // heavy (long-K / unskipped) rows launch first for causal modes
    const int by = (MODE >= 2) ? (gridDim.y - 1 - blockIdx.y) : blockIdx.y;
    const int masked = maskedp ? *maskedp : 1;
    if (MODE == 2 && masked && bx > by) return;      // fully-masked tile
    int kmax = K;
    if (MODE == 3 && masked) kmax = min(K, (by + 1) * 128);

    A  += (long)bz * strideAb;
    Bt += (long)bz * strideBb;

    // two BK=32 sub-tiles of A (128x32) + two of B (128x32)
    __shared__ __align__(16) f16 smem[256 * 64];
    f16* sA = smem;                    // halves at h*4096
    f16* sB = smem + 128 * 64;

    const int tid  = threadIdx.x;
    const int wave = tid >> 6, lane = tid & 63;
    const int wrow = wave >> 1, wcol = wave & 1;
    const int l31 = lane & 31, hi = lane >> 5;
    const int mBase = by * 128, nBase = bx * 128;
    const int mrow = wrow * (32 * MI);   // wave m-offset within tile

    f32x16 acc[MI][2];
#pragma unroll
    for (int i = 0; i < MI; ++i)
#pragma unroll
        for (int j = 0; j < 2; ++j)
#pragma unroll
            for (int e = 0; e < 16; ++e)
                acc[i][j][e] = 0.f;

    // pointer-bumped staging addresses (+64 f16 per outer iter)
    const f16* aP[RND];
    const f16* bP[RND];
#pragma unroll
    for (int r = 0; r < RND; ++r) {
        aP[r] = A  + (long)(mBase + ((r * NT + tid) >> 2)) * lda + ((tid * 8) & 31);
        bP[r] = Bt + (long)(nBase + ((r * NT + tid) >> 2)) * ldb + ((tid * 8) & 31);
    }
    const int ldsOff = wave * 512;

    const int nT = kmax >> 6;          // K-step 64
    for (int kt = 0; kt < nT; ++kt) {
#pragma unroll
        for (int h = 0; h < 2; ++h)
#pragma unroll
            for (int r = 0; r < RND; ++r) {
                async_ld16(aP[r] + h * 32, &sA[h * 4096 + r * (NT * 8) + ldsOff]);
                async_ld16(bP[r] + h * 32, &sB[h * 4096 + r * (NT * 8) + ldsOff]);
            }
#pragma unroll
        for (int r = 0; r < RND; ++r) { aP[r] += 64; bP[r] += 64; }
        __syncthreads();

#pragma unroll
        for (int h = 0; h < 2; ++h) {
#pragma unroll
            for (int kk = 0; kk < 2; ++kk) {      // two K=16 steps per BK32
                const int kcol = kk * 16 + hi * 8;
                f16x8 af[MI], bf[2];
#pragma unroll
                for (int i = 0; i < MI; ++i)
                    af[i] = *(const f16x8*)&sA[h * 4096 + (mrow + i * 32 + l31) * 32 + kcol];
#pragma unroll
                for (int j = 0; j < 2; ++j)
                    bf[j] = *(const f16x8*)&sB[h * 4096 + (wcol * 64 + j * 32 + l31) * 32 + kcol];
#pragma unroll
                for (int i = 0; i < MI; ++i)
#pragma unroll
                    for (int j = 0; j < 2; ++j)
                        acc[i][j] = __builtin_amdgcn_mfma_f32_32x32x16_f16(af[i], bf[j], acc[i][j], 0, 0, 0);
            }
        }
        __syncthreads();
    }

    // ---- epilogues. C/D: col=l31, row=(reg&3)+8*(reg>>2)+4*hi ----
    if (MODE == 0) {
        const int seg = nBase >> 10;
        const float* bs = (seg == 0) ? b_q : (seg == 1) ? b_k : b_v;
        const int lcb = (nBase & 1023) + wcol * 64;
        float bvv[2];
#pragma unroll
        for (int j = 0; j < 2; ++j) bvv[j] = bs[lcb + j * 32 + l31];

        if (seg < 2) {
            f16* dst = (seg == 0) ? (f16*)C0 : (f16*)C1;
#pragma unroll
            for (int i = 0; i < MI; ++i)
#pragma unroll
                for (int j = 0; j < 2; ++j)
#pragma unroll
                    for (int reg = 0; reg < 16; ++reg) {
                        const int row = mBase + mrow + i * 32 + 4 * hi + (reg & 3) + 8 * (reg >> 2);
                        dst[(long)row * 1024 + lcb + j * 32 + l31] = (f16)(acc[i][j][reg] + bvv[j]);
                    }
        } else {
            // V: transpose tile through LDS, store coalesced along s.
            const int b = mBase >> 11, s0 = mBase & 2047;
            f16* epiT = smem;   // 64 x 136 f16
#pragma unroll
            for (int hh = 0; hh < 2; ++hh) {
                if (wcol == hh) {
#pragma unroll
                    for (int i = 0; i < MI; ++i)
#pragma unroll
                        for (int j = 0; j < 2; ++j)
#pragma unroll
                            for (int g = 0; g < 4; ++g) {
                                f16x4v pk;
#pragma unroll
                                for (int rr = 0; rr < 4; ++rr)
                                    pk[rr] = (f16)(acc[i][j][g * 4 + rr] + bvv[j]);
                                const int e2 = j * 32 + l31;
                                const int sl = mrow + i * 32 + 4 * hi + 8 * g;
                                *(f16x4v*)&epiT[e2 * 136 + sl] = pk;
                            }
                }
                __syncthreads();
                const int er = tid >> 2;
                f16* dst = (f16*)C2 +
                    ((long)b * 1024 + (nBase & 1023) + hh * 64 + er) * 2048 + s0;
#pragma unroll
                for (int cc = 0; cc < 4; ++cc) {
                    const int ch = (tid & 3) + cc * 4;
                    *(f16x8*)&dst[ch * 8] = *(const f16x8*)&epiT[er * 136 + ch * 8];
                }
                __syncthreads();
            }
        }
    } else if (MODE == 2) {
        f16* Crow = (f16*)C0 + (long)bz * strideCb;
        float* rsb = rowsum + bz * 2048;
        const int colb = nBase + wcol * 64;
#pragma unroll
        for (int g = 0; g < 4; ++g) {
            const int q0 = mBase + mrow + 4 * hi + 8 * g;
            float rs[4] = {0.f, 0.f, 0.f, 0.f};
#pragma unroll
            for (int j = 0; j < 2; ++j)
#pragma unroll
                for (int rr = 0; rr < 4; ++rr) {
                    const int row = q0 + rr;
                    const int col = colb + j * 32 + l31;
                    float e = __expf(acc[0][j][g * 4 + rr] * 0.03125f);
                    if (masked && col > row) e = 0.f;
                    const f16 hv = (f16)e;
                    Crow[(long)row * 2048 + col] = hv;
                    rs[rr] += (float)hv;
                }
#pragma unroll
            for (int rr = 0; rr < 4; ++rr) {
                float s = rs[rr];
                s += __shfl_xor(s, 1);
                s += __shfl_xor(s, 2);
                s += __shfl_xor(s, 4);
                s += __shfl_xor(s, 8);
                s += __shfl_xor(s, 16);   // stays within the 32-lane half
                if (l31 == 0) atomicAdd(&rsb[q0 + rr], s);
            }
        }
    } else {  // MODE 3
        float* Crow = (float*)C0 + (long)bz * strideCb;
        const float* rsb = rowsum + bz * 2048;
        const int colb = nBase + wcol * 64;
#pragma unroll
        for (int g = 0; g < 4; ++g) {
            const int q0 = mBase + mrow + 4 * hi + 8 * g;
#pragma unroll
            for (int rr = 0; rr < 4; ++rr) {
                const float inv = 1.f / rsb[q0 + rr];
#pragma unroll
                for (int j = 0; j < 2; ++j)
                    Crow[(long)(q0 + rr) * 1024 + colb + j * 32 + l31] =
                        acc[0][j][g * 4 + rr] * inv;
            }
        }
    }
}

// fused fp32->f16 conversion: input (8192 row-blocks) + 3 weights (3072).
__global__ void cvt_all(const float* __restrict__ inp, const float* __restrict__ W0,
                        const float* __restrict__ W1, const float* __restrict__ W2,
                        f16* __restrict__ inp16, f16* __restrict__ W3)
{
    const int bid = blockIdx.x;
    const float* src;
    f16* dst;
    int i;
    if (bid < 8192) {               // input: 8192 * 256 * 4 fp32 = 8M elems
        src = inp;  dst = inp16;  i = bid * 256 + threadIdx.x;
    } else {
        const int wb = bid - 8192;  // 3072 blocks over 3 weights
        const int which = wb >> 10;
        src = (which == 0) ? W0 : (which == 1) ? W1 : W2;
        dst = W3 + (long)which * 1024 * 1024;
        i = (wb & 1023) * 256 + threadIdx.x;
    }
    const float4 v = ((const float4*)src)[i];
    f16x4v o;
    o[0] = (f16)v.x; o[1] = (f16)v.y; o[2] = (f16)v.z; o[3] = (f16)v.w;
    ((f16x4v*)dst)[i] = o;
}

extern "C" void kernel_launch(void* const* d_in, const int* in_sizes, int n_in,
                              void* d_out, int out_size, void* d_ws, size_t ws_size,
                              hipStream_t stream)
{
    const float* inp = (const float*)d_in[0];
    const int* masked = (const int*)d_in[1];
    const float* Wq = (const float*)d_in[2];
    const float* bq = (const float*)d_in[3];
    const float* Wk = (const float*)d_in[4];
    const float* bk = (const float*)d_in[5];
    const float* Wv = (const float*)d_in[6];
    const float* bv = (const float*)d_in[7];
    float* out = (float*)d_out;

    const int Bb = 4, S = 2048, E = 1024;
    const long nTok = (long)Bb * S;   // 8192

    // workspace (~102 MB). W3 segments must stay contiguous (one Bt operand).
    char* ws = (char*)d_ws;
    f16* inp16 = (f16*)ws;   ws += nTok * E * 2;         // 16 MB
    f16* W3    = (f16*)ws;   ws += (long)3 * E * E * 2;  //  6 MB
    f16* Q16   = (f16*)ws;   ws += nTok * E * 2;         // 16 MB
    f16* K16   = (f16*)ws;   ws += nTok * E * 2;         // 16 MB
    f16* Vt16  = (f16*)ws;   ws += nTok * E * 2;         // 16 MB ([b][e][s])
    f16* P16   = (f16*)ws;   ws += (long)Bb * S * S * 2; // 32 MB
    float* rsum = (float*)ws; ws += nTok * 4;            // 32 KB

    dim3 blk(256);

    hipMemsetAsync(rsum, 0, nTok * 4, stream);
    cvt_all<<<8192 + 3072, blk, 0, stream>>>(inp, Wq, Wk, Wv, inp16, W3);

    // fused QKV: A = inp (8192x1024 tokens), Bt = W3 (3072x1024)
    gemm_bt<0><<<dim3(3 * E / 128, (int)(nTok / 128), 1), blk, 0, stream>>>(
        inp16, 0, E, W3, 0, E, bq, bk, bv, nullptr,
        Q16, K16, Vt16, 0, E, nullptr);

    // P = exp(QK^T/32) + rowsum atomics (128x128 tiles, 8-wave blocks,
    // causal skip, heavy rows first)
    gemm_bt<2><<<dim3(S / 128, S / 128, Bb), dim3(512), 0, stream>>>(
        Q16, (long)S * E, E, K16, (long)S * E, E, nullptr, nullptr, nullptr, rsum,
        P16, nullptr, nullptr, (long)S * S, E, masked);

    // out = (P @ V)/rowsum (128x128 tiles, 8-wave blocks, K causal-limited)
    gemm_bt<3><<<dim3(E / 128, S / 128, Bb), dim3(512), 0, stream>>>(
        P16, (long)S * S, S, Vt16, (long)E * S, S, nullptr, nullptr, nullptr, rsum,
        out, nullptr, nullptr, (long)S * E, S, masked);
}